// Round 12
// baseline (97.113 us; speedup 1.0000x reference)
//
#include <hip/hip_runtime.h>
#include <hip/hip_bf16.h>

#define EPS 1e-3f

typedef float f32x4 __attribute__((ext_vector_type(4)));
typedef float f4    __attribute__((ext_vector_type(4)));
typedef short short8 __attribute__((ext_vector_type(8)));

__device__ __forceinline__ unsigned short f2bf(float f) {
    unsigned u = __float_as_uint(f);
    u += 0x7FFFu + ((u >> 16) & 1u);   // round-to-nearest-even
    return (unsigned short)(u >> 16);
}
__device__ __forceinline__ float bf2f(unsigned s) {
    return __uint_as_float(s << 16);
}
// packed f32x2 -> bf16x2 (RNE)
__device__ __forceinline__ unsigned pk2(float lo, float hi) {
    float2 t; t.x = lo; t.y = hi;
    __hip_bfloat162 hh = __float22bfloat162_rn(t);
    return *reinterpret_cast<unsigned*>(&hh);
}

// ---------------------------------------------------------------------------
// Prep: fold BN1/BN2 into attention weights, transpose all weights to bf16
// ---------------------------------------------------------------------------
__global__ void prep_kernel(const float* __restrict__ w3,
                            const float* __restrict__ g1, const float* __restrict__ be1,
                            const float* __restrict__ m1, const float* __restrict__ v1,
                            const float* __restrict__ wa1, const float* __restrict__ ba1,
                            const float* __restrict__ g2, const float* __restrict__ be2,
                            const float* __restrict__ m2, const float* __restrict__ v2,
                            const float* __restrict__ wa2, const float* __restrict__ ba2,
                            unsigned short* __restrict__ w3T,
                            unsigned short* __restrict__ wa1T,
                            unsigned short* __restrict__ wa2T,
                            float* __restrict__ b_a1p, float* __restrict__ b_a2p)
{
    const int blk = blockIdx.x;
    const int tid = threadIdx.x;
    if (blk < 64) {
        #pragma unroll
        for (int i = 0; i < 4; ++i) {
            int f = blk * 4 + i;
            w3T[f * 256 + tid] = f2bf(w3[tid * 256 + f]);
        }
    } else if (blk < 96) {
        int a = blk - 64;
        int c = tid;
        float s1 = rsqrtf(v1[c] + EPS) * g1[c];
        float wv = wa1[c * 32 + a];
        wa1T[a * 256 + c] = f2bf(wv * s1);
        float part = (be1[c] - m1[c] * s1) * wv;
        __shared__ float red[4];
        #pragma unroll
        for (int off = 32; off > 0; off >>= 1) part += __shfl_down(part, off);
        if ((tid & 63) == 0) red[tid >> 6] = part;
        __syncthreads();
        if (tid == 0) b_a1p[a] = ba1[a] + red[0] + red[1] + red[2] + red[3];
    } else {
        int f = tid;
        float acc = ba2[f];
        #pragma unroll
        for (int a = 0; a < 32; ++a) {
            float s2 = rsqrtf(v2[a] + EPS) * g2[a];
            float wv = wa2[a * 256 + f];
            wa2T[f * 32 + a] = f2bf(wv * s2);
            acc += (be2[a] - m2[a] * s2) * wv;
        }
        b_a2p[f] = acc;
    }
}

// ---------------------------------------------------------------------------
// K1: y = x @ w3 (no bias, bf16 -> ws) AND a1 = relu(x_bn @ wa1') (bf16 ws).
// Block = HALF image row (32 px), 256 thr / 4 waves; grid 2048 = 8/CU x 256.
// LDS 16 KB (xs half-row bf16, XOR-swizzled) -> 8 blocks/CU, 32 waves/CU.
// ONE barrier. Wave w: GEMM1 tile (a-half w>>1, px-quarter w&1) = 8 MFMA;
// main GEMM 64-f slice x 32 px = 64 MFMA, y stored straight from accs.
// y layout: [row][px 0..63][f 0..255] bf16 (32 KB/row).
// a1g layout: [row][px 0..63][a 0..31] bf16.
// ---------------------------------------------------------------------------
__global__ __launch_bounds__(256, 8)
void gemm_y_kernel(const float* __restrict__ x,
                   const unsigned short* __restrict__ w3T,
                   const unsigned short* __restrict__ wa1T,
                   const float* __restrict__ b_a1p,
                   unsigned short* __restrict__ yg,
                   unsigned short* __restrict__ a1g)
{
    __shared__ __align__(16) unsigned char lds[16384];

    const int tid = threadIdx.x;
    const int bid = blockIdx.x;
    const int g    = (bid & 7) * 256 + (bid >> 3);   // XCD swizzle (2048%8==0)
    const int row  = g >> 1;
    const int half = g & 1;

    const int wv   = tid >> 6;
    const int lane = tid & 63;
    const int cl   = lane & 15;
    const int lkg  = lane >> 4;

    // ------- stage half-row -> xs bf16 (swizzled) --------------------------
    const f4* pc = (const f4*)x + (size_t)row * 4096 + half * 2048;
    #pragma unroll
    for (int j = 0; j < 8; ++j) {
        int v  = tid + j * 256;        // f4 index 0..2047
        int px = v >> 6;               // local px 0..31
        int c4 = v & 63;
        f4 a0 = pc[v];
        uint2 pk;
        pk.x = pk2(a0.x, a0.y);
        pk.y = pk2(a0.z, a0.w);
        unsigned ad = (unsigned)px * 512u +
                      (((unsigned)c4 * 8u) ^ (((unsigned)px & 7u) << 4));
        *(uint2*)(lds + ad) = pk;
    }
    __syncthreads();

    // ------- GEMM1: a1 tile (at = wv>>1, pxt = wv&1), 8 MFMA ---------------
    {
        const int at  = wv >> 1;
        const int pxt = wv & 1;
        const int bpx = pxt * 16 + cl;             // local px of B-frag
        f32x4 acc1 = (f32x4){0,0,0,0};
        #pragma unroll
        for (int kk = 0; kk < 8; ++kk) {
            short8 afr = *(const short8*)(wa1T + ((at * 16 + cl) * 256 + kk * 32 + lkg * 8));
            unsigned ad = (unsigned)bpx * 512u +
                          (((unsigned)(kk * 64 + lkg * 16)) ^ (((unsigned)bpx & 7u) << 4));
            short8 bfr = *(const short8*)(lds + ad);
            acc1 = __builtin_amdgcn_mfma_f32_16x16x32_bf16(afr, bfr, acc1, 0, 0, 0);
        }
        // C: row a = at*16+lkg*4+r, col px = pxt*16+cl
        f4 bb1 = *(const f4*)(b_a1p + at * 16 + lkg * 4);
        float v0 = acc1[0] + bb1.x; v0 = v0 > 0.f ? v0 : 0.f;
        float v1 = acc1[1] + bb1.y; v1 = v1 > 0.f ? v1 : 0.f;
        float v2 = acc1[2] + bb1.z; v2 = v2 > 0.f ? v2 : 0.f;
        float v3 = acc1[3] + bb1.w; v3 = v3 > 0.f ? v3 : 0.f;
        uint2 st;
        st.x = pk2(v0, v1);
        st.y = pk2(v2, v3);
        int gp = half * 32 + pxt * 16 + cl;
        *(uint2*)(a1g + (size_t)row * 2048 + gp * 32 + at * 16 + lkg * 4) = st;
    }

    // ------- main GEMM: 64-f slice x 32 px ---------------------------------
    const int F0 = wv * 64;
    f32x4 acc[4][2];
    #pragma unroll
    for (int ft = 0; ft < 4; ++ft)
        #pragma unroll
        for (int pt = 0; pt < 2; ++pt) acc[ft][pt] = (f32x4){0,0,0,0};

    #pragma unroll
    for (int kk = 0; kk < 8; ++kk) {
        short8 xfr[2];
        #pragma unroll
        for (int pt = 0; pt < 2; ++pt) {
            int px = pt * 16 + cl;
            unsigned ad = (unsigned)px * 512u +
                          (((unsigned)(kk * 64 + lkg * 16)) ^ (((unsigned)px & 7u) << 4));
            xfr[pt] = *(const short8*)(lds + ad);
        }
        #pragma unroll
        for (int ft = 0; ft < 4; ++ft) {
            short8 afr = *(const short8*)(w3T + ((F0 + ft * 16 + cl) * 256 + kk * 32 + lkg * 8));
            acc[ft][0] = __builtin_amdgcn_mfma_f32_16x16x32_bf16(afr, xfr[0], acc[ft][0], 0, 0, 0);
            acc[ft][1] = __builtin_amdgcn_mfma_f32_16x16x32_bf16(afr, xfr[1], acc[ft][1], 0, 0, 0);
        }
    }

    // ------- y store (bf16, straight from accs) ----------------------------
    unsigned short* yrow = yg + (size_t)row * 16384;
    #pragma unroll
    for (int ft = 0; ft < 4; ++ft) {
        int f0 = F0 + ft * 16 + lkg * 4;
        #pragma unroll
        for (int pt = 0; pt < 2; ++pt) {
            int gp = half * 32 + pt * 16 + cl;
            uint2 o;
            o.x = pk2(acc[ft][pt][0], acc[ft][pt][1]);
            o.y = pk2(acc[ft][pt][2], acc[ft][pt][3]);
            *(uint2*)(yrow + gp * 256 + f0) = o;
        }
    }
}

// ---------------------------------------------------------------------------
// K2: vs = vertical-3-sum(y) (L3-hot bf16) | GEMM2+exp | ONE barrier |
// horizontal fold + out = e*invS*(s + cnt*b3).
// Block = HALF image row, 256 thr / 4 waves; grid 2048 = 8/CU x 256.
// LDS 17920: vs[0,17408) = [34 px][256 f] bf16 XOR-swizzled (px -1..+32 of
// this half, cross-half halo included); psum[17408,17920) = [4 wv][32 px].
// Wave: 64-f slice; GEMM2 slice = 4ft x 2pt = 8 MFMA; e stays lane-local
// (C-layout == epilogue layout). No main GEMM here.
// ---------------------------------------------------------------------------
__global__ __launch_bounds__(256, 8)
void boxmul_kernel(const unsigned short* __restrict__ yg,
                   const unsigned short* __restrict__ a1g,
                   const float* __restrict__ b3,
                   const unsigned short* __restrict__ wa2T,
                   const float* __restrict__ b_a2p,
                   float* __restrict__ out)
{
    __shared__ __align__(16) unsigned char lds[17920];

    const int tid = threadIdx.x;
    const int bid = blockIdx.x;
    const int g    = (bid & 7) * 256 + (bid >> 3);   // XCD swizzle
    const int row  = g >> 1;
    const int half = g & 1;
    const int h    = row & 63;

    const int wv   = tid >> 6;
    const int lane = tid & 63;
    const int cl   = lane & 15;
    const int lkg  = lane >> 4;
    const int F0   = wv * 64;

    const bool hm = (h > 0), hp = (h < 63);
    const unsigned char* ybase = (const unsigned char*)yg + (size_t)row * 32768;

    // ------- stage: vertical 3-sum of y -> vs (34 px columns) --------------
    #pragma unroll
    for (int i = 0; i < 5; ++i) {
        int a = tid + i * 256;
        if (a < 1088) {
            int pl = a >> 5;               // vs row 0..33
            int cb = (a & 31) * 16;        // byte offset in 512B px row
            int gp = half * 32 + pl - 1;   // global px
            uint4 o = {0u, 0u, 0u, 0u};
            if (gp >= 0 && gp < 64) {
                int off = gp * 512 + cb;
                uint4 z4 = {0u, 0u, 0u, 0u};
                uint4 q1 = *(const uint4*)(ybase + off);
                uint4 q0 = hm ? *(const uint4*)(ybase - 32768 + off) : z4;
                uint4 q2 = hp ? *(const uint4*)(ybase + 32768 + off) : z4;
                float s0 = bf2f(q0.x & 0xffffu) + bf2f(q1.x & 0xffffu) + bf2f(q2.x & 0xffffu);
                float s1 = bf2f(q0.x >> 16)     + bf2f(q1.x >> 16)     + bf2f(q2.x >> 16);
                float s2 = bf2f(q0.y & 0xffffu) + bf2f(q1.y & 0xffffu) + bf2f(q2.y & 0xffffu);
                float s3 = bf2f(q0.y >> 16)     + bf2f(q1.y >> 16)     + bf2f(q2.y >> 16);
                float s4 = bf2f(q0.z & 0xffffu) + bf2f(q1.z & 0xffffu) + bf2f(q2.z & 0xffffu);
                float s5 = bf2f(q0.z >> 16)     + bf2f(q1.z >> 16)     + bf2f(q2.z >> 16);
                float s6 = bf2f(q0.w & 0xffffu) + bf2f(q1.w & 0xffffu) + bf2f(q2.w & 0xffffu);
                float s7 = bf2f(q0.w >> 16)     + bf2f(q1.w >> 16)     + bf2f(q2.w >> 16);
                o.x = pk2(s0, s1); o.y = pk2(s2, s3);
                o.z = pk2(s4, s5); o.w = pk2(s6, s7);
            }
            unsigned ad = (unsigned)pl * 512u +
                          (((unsigned)cb) ^ (((unsigned)pl & 7u) << 4));
            *(uint4*)(lds + ad) = o;
        }
    }

    // ------- GEMM2 slice + exp (independent of vs) -------------------------
    uint2 ep[4][2];
    float ps[2];
    {
        const unsigned short* a1row = a1g + (size_t)row * 2048;
        f4 bb2[4];
        #pragma unroll
        for (int ft = 0; ft < 4; ++ft)
            bb2[ft] = *(const f4*)(b_a2p + F0 + ft * 16 + lkg * 4);
        #pragma unroll
        for (int pt = 0; pt < 2; ++pt) {
            int gp = half * 32 + pt * 16 + cl;
            short8 bfr = *(const short8*)(a1row + gp * 32 + lkg * 8);
            float ssum = 0.f;
            #pragma unroll
            for (int ft = 0; ft < 4; ++ft) {
                short8 wfr = *(const short8*)(wa2T + ((F0 + ft * 16 + cl) * 32 + lkg * 8));
                f32x4 z = {0, 0, 0, 0};
                f32x4 a2 = __builtin_amdgcn_mfma_f32_16x16x32_bf16(wfr, bfr, z, 0, 0, 0);
                float e0, e1, e2, e3;
                float v0 = a2[0] + bb2[ft][0]; v0 = v0 > 0.f ? v0 : 0.f; e0 = __expf(v0);
                float v1 = a2[1] + bb2[ft][1]; v1 = v1 > 0.f ? v1 : 0.f; e1 = __expf(v1);
                float v2 = a2[2] + bb2[ft][2]; v2 = v2 > 0.f ? v2 : 0.f; e2 = __expf(v2);
                float v3 = a2[3] + bb2[ft][3]; v3 = v3 > 0.f ? v3 : 0.f; e3 = __expf(v3);
                ssum += (e0 + e1) + (e2 + e3);
                ep[ft][pt].x = pk2(e0, e1);
                ep[ft][pt].y = pk2(e2, e3);
            }
            ssum += __shfl_xor(ssum, 16);
            ssum += __shfl_xor(ssum, 32);
            ps[pt] = ssum;             // replicated across lkg
        }
        // one writer per local px: lanes lkg<2 cover px = lkg*16+cl
        if (lkg < 2) {
            float wsum = lkg ? ps[1] : ps[0];
            *(float*)(lds + 17408 + wv * 128 + (lkg * 16 + cl) * 4) = wsum;
        }
    }

    __syncthreads();   // vs + psum published

    // ------- epilogue: horizontal fold + multiply + store ------------------
    const int rh = (h == 0 || h == 63) ? 2 : 3;
    float* orow = out + (size_t)row * 16384;
    #pragma unroll
    for (int pt = 0; pt < 2; ++pt) {
        int pxl = pt * 16 + cl;
        int gp  = half * 32 + pxl;
        float den = 0.f;
        #pragma unroll
        for (int w = 0; w < 4; ++w)
            den += *(const float*)(lds + 17408 + w * 128 + pxl * 4);
        float is = 1.f / den;
        float cnt = (float)(rh * ((gp == 0 || gp == 63) ? 2 : 3));
        #pragma unroll
        for (int ft = 0; ft < 4; ++ft) {
            int f0 = F0 + ft * 16 + lkg * 4;
            float s0 = 0.f, s1 = 0.f, s2 = 0.f, s3 = 0.f;
            #pragma unroll
            for (int d = 0; d < 3; ++d) {
                int pl = pxl + d;          // vs rows pxl, pxl+1, pxl+2
                unsigned ad = (unsigned)pl * 512u +
                              (((unsigned)(f0 * 2)) ^ (((unsigned)pl & 7u) << 4));
                uint2 q = *(const uint2*)(lds + ad);
                s0 += bf2f(q.x & 0xffffu); s1 += bf2f(q.x >> 16);
                s2 += bf2f(q.y & 0xffffu); s3 += bf2f(q.y >> 16);
            }
            f4 b3v = *(const f4*)(b3 + f0);
            uint2 ev = ep[ft][pt];
            f4 o;
            o.x = bf2f(ev.x & 0xffffu) * is * (s0 + cnt * b3v.x);
            o.y = bf2f(ev.x >> 16)     * is * (s1 + cnt * b3v.y);
            o.z = bf2f(ev.y & 0xffffu) * is * (s2 + cnt * b3v.z);
            o.w = bf2f(ev.y >> 16)     * is * (s3 + cnt * b3v.w);
            *(f4*)(orow + gp * 256 + f0) = o;
        }
    }
}

extern "C" void kernel_launch(void* const* d_in, const int* in_sizes, int n_in,
                              void* d_out, int out_size, void* d_ws, size_t ws_size,
                              hipStream_t stream)
{
    const float* x   = (const float*)d_in[0];
    const float* w3  = (const float*)d_in[1];
    const float* b3  = (const float*)d_in[2];
    const float* g1  = (const float*)d_in[3];
    const float* be1 = (const float*)d_in[4];
    const float* m1  = (const float*)d_in[5];
    const float* v1  = (const float*)d_in[6];
    const float* wa1 = (const float*)d_in[7];
    const float* ba1 = (const float*)d_in[8];
    const float* g2  = (const float*)d_in[9];
    const float* be2 = (const float*)d_in[10];
    const float* m2  = (const float*)d_in[11];
    const float* v2  = (const float*)d_in[12];
    const float* wa2 = (const float*)d_in[13];
    const float* ba2 = (const float*)d_in[14];

    unsigned char* ws = (unsigned char*)d_ws;
    unsigned short* w3T   = (unsigned short*)(ws);
    unsigned short* wa1T  = (unsigned short*)(ws + 131072);
    unsigned short* wa2T  = (unsigned short*)(ws + 147456);
    float*          b_a1p = (float*)(ws + 163840);
    float*          b_a2p = (float*)(ws + 163968);
    unsigned short* a1g   = (unsigned short*)(ws + 196608);             // 4 MB
    unsigned short* yg    = (unsigned short*)(ws + 196608 + 4194304);   // 32 MB

    hipLaunchKernelGGL(prep_kernel, dim3(97), dim3(256), 0, stream,
                       w3, g1, be1, m1, v1, wa1, ba1, g2, be2, m2, v2, wa2, ba2,
                       w3T, wa1T, wa2T, b_a1p, b_a2p);
    hipLaunchKernelGGL(gemm_y_kernel, dim3(2048), dim3(256), 0, stream,
                       x, w3T, wa1T, b_a1p, yg, a1g);
    hipLaunchKernelGGL(boxmul_kernel, dim3(2048), dim3(256), 0, stream,
                       yg, a1g, b3, wa2T, b_a2p, (float*)d_out);
}

// Round 13
// 75.079 us; speedup vs baseline: 1.2935x; 1.2935x over previous
//
#include <hip/hip_runtime.h>
#include <hip/hip_bf16.h>

#define EPS 1e-3f

typedef float f32x4 __attribute__((ext_vector_type(4)));
typedef float f4    __attribute__((ext_vector_type(4)));
typedef short short8 __attribute__((ext_vector_type(8)));

__device__ __forceinline__ unsigned short f2bf(float f) {
    unsigned u = __float_as_uint(f);
    u += 0x7FFFu + ((u >> 16) & 1u);   // round-to-nearest-even
    return (unsigned short)(u >> 16);
}
__device__ __forceinline__ float bf2f(unsigned s) {
    return __uint_as_float(s << 16);
}
// packed f32x2 -> bf16x2 (RNE)
__device__ __forceinline__ unsigned pk2(float lo, float hi) {
    float2 t; t.x = lo; t.y = hi;
    __hip_bfloat162 hh = __float22bfloat162_rn(t);
    return *reinterpret_cast<unsigned*>(&hh);
}

// ---------------------------------------------------------------------------
// Prep: fold BN1/BN2 into attention weights, transpose all weights to bf16
// ---------------------------------------------------------------------------
__global__ void prep_kernel(const float* __restrict__ w3,
                            const float* __restrict__ g1, const float* __restrict__ be1,
                            const float* __restrict__ m1, const float* __restrict__ v1,
                            const float* __restrict__ wa1, const float* __restrict__ ba1,
                            const float* __restrict__ g2, const float* __restrict__ be2,
                            const float* __restrict__ m2, const float* __restrict__ v2,
                            const float* __restrict__ wa2, const float* __restrict__ ba2,
                            unsigned short* __restrict__ w3T,
                            unsigned short* __restrict__ wa1T,
                            unsigned short* __restrict__ wa2T,
                            float* __restrict__ b_a1p, float* __restrict__ b_a2p)
{
    const int blk = blockIdx.x;
    const int tid = threadIdx.x;
    if (blk < 64) {
        #pragma unroll
        for (int i = 0; i < 4; ++i) {
            int f = blk * 4 + i;
            w3T[f * 256 + tid] = f2bf(w3[tid * 256 + f]);
        }
    } else if (blk < 96) {
        int a = blk - 64;
        int c = tid;
        float s1 = rsqrtf(v1[c] + EPS) * g1[c];
        float wv = wa1[c * 32 + a];
        wa1T[a * 256 + c] = f2bf(wv * s1);
        float part = (be1[c] - m1[c] * s1) * wv;
        __shared__ float red[4];
        #pragma unroll
        for (int off = 32; off > 0; off >>= 1) part += __shfl_down(part, off);
        if ((tid & 63) == 0) red[tid >> 6] = part;
        __syncthreads();
        if (tid == 0) b_a1p[a] = ba1[a] + red[0] + red[1] + red[2] + red[3];
    } else {
        int f = tid;
        float acc = ba2[f];
        #pragma unroll
        for (int a = 0; a < 32; ++a) {
            float s2 = rsqrtf(v2[a] + EPS) * g2[a];
            float wv = wa2[a * 256 + f];
            wa2T[f * 32 + a] = f2bf(wv * s2);
            acc += (be2[a] - m2[a] * s2) * wv;
        }
        b_a2p[f] = acc;
    }
}

// ---------------------------------------------------------------------------
// Kernel A: a1 = relu(x_bn @ wa1') (bf16 ws) AND deninv[px] = 1/sum_f e[px,f]
// (f32 ws).  Block = one image row, 4 waves x 16 px, tiny LDS, no barrier.
// The denominator GEMM2 (16 MFMA + 64 exp / lane) fills this kernel's idle
// latency slots; it uses the bf16-ROUNDED a1 (read back from the LDS bounce)
// so den exactly matches fused2's e-recompute.
// a1g layout: [row][px 0..63][a 0..31] bf16 (4 KB per row).
// ---------------------------------------------------------------------------
__global__ __launch_bounds__(256, 8)
void attn1_kernel(const float* __restrict__ x,
                  const unsigned short* __restrict__ wa1T,
                  const unsigned short* __restrict__ wa2T,
                  const float* __restrict__ b_a1p,
                  const float* __restrict__ b_a2p,
                  unsigned short* __restrict__ a1g,
                  float* __restrict__ deninv_g)
{
    __shared__ __align__(16) unsigned char lds[5120];

    const int tid = threadIdx.x;
    const int bid = blockIdx.x;
    const int row = (bid & 7) * 128 + (bid >> 3);   // XCD swizzle

    const int wv   = tid >> 6;
    const int lane = tid & 63;
    const int cl   = lane & 15;
    const int lkg  = lane >> 4;

    const float* xr = x + ((size_t)row * 64 + wv * 16 + cl) * 256;

    f32x4 acc1[2];
    acc1[0] = (f32x4){0,0,0,0};
    acc1[1] = (f32x4){0,0,0,0};
    #pragma unroll
    for (int kk = 0; kk < 8; ++kk) {
        f4 u0 = *(const f4*)(xr + kk * 32 + lkg * 8);
        f4 u1 = *(const f4*)(xr + kk * 32 + lkg * 8 + 4);
        unsigned apv[4];
        apv[0] = pk2(u0.x, u0.y); apv[1] = pk2(u0.z, u0.w);
        apv[2] = pk2(u1.x, u1.y); apv[3] = pk2(u1.z, u1.w);
        short8 afr = *reinterpret_cast<short8*>(apv);
        #pragma unroll
        for (int t = 0; t < 2; ++t) {
            short8 bfr = *(const short8*)(wa1T + ((t * 16 + cl) * 256 + kk * 32 + lkg * 8));
            acc1[t] = __builtin_amdgcn_mfma_f32_16x16x32_bf16(afr, bfr, acc1[t], 0, 0, 0);
        }
    }
    // C layout: row m = lkg*4+r (px = wv*16+m), col a = t*16+cl.
    // bounce via per-wave LDS (pitch 80 B), then one coalesced 16 B store/lane
    const unsigned a1base = (unsigned)wv * 1280u;
    #pragma unroll
    for (int t = 0; t < 2; ++t) {
        int a = t * 16 + cl;
        float bb = b_a1p[a];
        #pragma unroll
        for (int r = 0; r < 4; ++r) {
            float vv = acc1[t][r] + bb;
            vv = vv > 0.f ? vv : 0.f;
            int m = lkg * 4 + r;
            *(unsigned short*)(lds + a1base + m * 80 + a * 2) = f2bf(vv);
        }
    }
    asm volatile("s_waitcnt lgkmcnt(0)" ::: "memory");
    __builtin_amdgcn_sched_barrier(0);
    uint4 v = *(const uint4*)(lds + a1base + (lane >> 2) * 80 + (lane & 3) * 16);
    *(uint4*)(a1g + (size_t)row * 2048 + wv * 512 + lane * 8) = v;

    // ------- GEMM2 full-f for own 16 px -> deninv (from bf16-rounded a1) ---
    {
        short8 a1f = *(const short8*)(lds + a1base + cl * 80 + lkg * 16);
        float ssum = 0.f;
        #pragma unroll
        for (int t = 0; t < 16; ++t) {
            short8 wfr = *(const short8*)(wa2T + ((t * 16 + cl) * 32 + lkg * 8));
            f32x4 z = {0, 0, 0, 0};
            f32x4 a2 = __builtin_amdgcn_mfma_f32_16x16x32_bf16(wfr, a1f, z, 0, 0, 0);
            f4 bb = *(const f4*)(b_a2p + t * 16 + lkg * 4);
            float v0 = a2[0] + bb.x; v0 = v0 > 0.f ? v0 : 0.f;
            float v1 = a2[1] + bb.y; v1 = v1 > 0.f ? v1 : 0.f;
            float v2 = a2[2] + bb.z; v2 = v2 > 0.f ? v2 : 0.f;
            float v3 = a2[3] + bb.w; v3 = v3 > 0.f ? v3 : 0.f;
            ssum += (__expf(v0) + __expf(v1)) + (__expf(v2) + __expf(v3));
        }
        ssum += __shfl_xor(ssum, 16);
        ssum += __shfl_xor(ssum, 32);
        if (lkg == 0)
            deninv_g[row * 64 + wv * 16 + cl] = 1.f / ssum;
    }
}

// ---------------------------------------------------------------------------
// Kernel B: stage(batched) | ONE barrier | {main GEMM + GEMM2/exp interleaved}
// | epilogue (no second barrier: deninv precomputed by attn1).
// Block = one image row, 8 waves, 1024 blocks = 2 exact residency rounds.
// Per wave: 32-f slice x 64 px; e lane-local (GEMM2 C-layout == main GEMM).
// LDS 32768: xs [64px][256c] bf16 XOR-swizzled.  launch_bounds(512,4).
// ---------------------------------------------------------------------------
__global__ __launch_bounds__(512, 4)
void fused2_kernel(const float* __restrict__ x,
                   const unsigned short* __restrict__ a1g,
                   const float* __restrict__ b3,
                   const unsigned short* __restrict__ w3T,
                   const unsigned short* __restrict__ wa2T,
                   const float* __restrict__ b_a2p,
                   const float* __restrict__ deninv_g,
                   float* __restrict__ out)
{
    __shared__ __align__(16) unsigned char lds[32768];

    const int tid = threadIdx.x;
    const int bid = blockIdx.x;
    const int row = (bid & 7) * 128 + (bid >> 3);   // XCD swizzle
    const int h   = row & 63;

    const int wv   = tid >> 6;
    const int lane = tid & 63;
    const int cl   = lane & 15;
    const int lkg  = lane >> 4;
    const int F0   = wv * 32;

    const size_t rowb = (size_t)row * 16384;
    const float* xrow = x + rowb;
    const bool hm = (h > 0), hp = (h < 63);
    const f4* pc = (const f4*)xrow;
    const f4* pm = (const f4*)(xrow - 16384);
    const f4* pp = (const f4*)(xrow + 16384);
    const f4 z4 = {0.f, 0.f, 0.f, 0.f};

    // ------- early-issue: inverse denominators for this lane's 4 px --------
    float isv[4];
    #pragma unroll
    for (int pt = 0; pt < 4; ++pt)
        isv[pt] = deninv_g[row * 64 + pt * 16 + cl];

    // ------- stage own 8-px strip: batched independent loads -> xs ---------
    {
        f4 lm[10], lc[10], lp[10];
        #pragma unroll
        for (int r = 0; r < 10; ++r) {
            int g  = wv * 8 - 1 + r;
            int gc = g < 0 ? 0 : (g > 63 ? 63 : g);
            int idx = gc * 64 + lane;
            lc[r] = pc[idx];
            lm[r] = hm ? pm[idx] : z4;
            lp[r] = hp ? pp[idx] : z4;
        }
        f4 vs[10];
        #pragma unroll
        for (int r = 0; r < 10; ++r) {
            int g = wv * 8 - 1 + r;
            f4 v = lm[r] + lc[r] + lp[r];
            vs[r] = (g >= 0 && g < 64) ? v : z4;
        }
        #pragma unroll
        for (int j = 0; j < 8; ++j) {
            f4 s = vs[j] + vs[j + 1] + vs[j + 2];
            int gw = wv * 8 + j;              // gw & 7 == j
            unsigned addr = (unsigned)gw * 512u +
                            (((unsigned)lane * 8u) ^ (((unsigned)j & 7u) << 4));
            uint2 pk;
            pk.x = pk2(s.x, s.y);
            pk.y = pk2(s.z, s.w);
            *(uint2*)(lds + addr) = pk;
        }
    }

    __syncthreads();   // xs published (the only barrier)

    // ------- merged region: main GEMM + GEMM2/exp interleaved --------------
    f32x4 acc[2][4];
    #pragma unroll
    for (int ft = 0; ft < 2; ++ft)
        #pragma unroll
        for (int pt = 0; pt < 4; ++pt) acc[ft][pt] = (f32x4){0,0,0,0};

    uint2 ep[2][4];                    // e packed bf16
    const unsigned short* a1row = a1g + (size_t)row * 2048;

    // GEMM2 weight frags (reused across all pt): 2 x short8 = 8 VGPR
    short8 wfr2[2];
    #pragma unroll
    for (int ft = 0; ft < 2; ++ft)
        wfr2[ft] = *(const short8*)(wa2T + ((F0 + ft * 16 + cl) * 32 + lkg * 8));
    f4 bb2[2];
    #pragma unroll
    for (int ft = 0; ft < 2; ++ft)
        bb2[ft] = *(const f4*)(b_a2p + F0 + ft * 16 + lkg * 4);

    #pragma unroll
    for (int kk = 0; kk < 8; ++kk) {
        // ---- main GEMM step ----
        short8 afr[2];
        #pragma unroll
        for (int ft = 0; ft < 2; ++ft)
            afr[ft] = *(const short8*)(w3T + ((F0 + ft * 16 + cl) * 256 + kk * 32 + lkg * 8));
        short8 xfr[4];
        #pragma unroll
        for (int pt = 0; pt < 4; ++pt) {
            unsigned px = (unsigned)(pt * 16 + cl);
            unsigned ad = px * 512u +
                          (((unsigned)(kk * 64 + lkg * 16)) ^ (((unsigned)px & 7u) << 4));
            xfr[pt] = *(const short8*)(lds + ad);
        }
        #pragma unroll
        for (int ft = 0; ft < 2; ++ft)
            #pragma unroll
            for (int pt = 0; pt < 4; ++pt)
                acc[ft][pt] = __builtin_amdgcn_mfma_f32_16x16x32_bf16(afr[ft], xfr[pt], acc[ft][pt], 0, 0, 0);

        // ---- GEMM2 pt-step on even kk: exp VALU overlaps MFMA pipe ----
        if ((kk & 1) == 0) {
            const int pt = kk >> 1;
            short8 bfr = *(const short8*)(a1row + ((pt * 16 + cl) * 32 + lkg * 8));
            f32x4 z = {0,0,0,0};
            f32x4 a2a = __builtin_amdgcn_mfma_f32_16x16x32_bf16(wfr2[0], bfr, z, 0, 0, 0);
            f32x4 a2b = __builtin_amdgcn_mfma_f32_16x16x32_bf16(wfr2[1], bfr, z, 0, 0, 0);
            float e0[4], e1[4];
            #pragma unroll
            for (int r = 0; r < 4; ++r) {
                float va = a2a[r] + bb2[0][r]; va = va > 0.f ? va : 0.f;
                float vb = a2b[r] + bb2[1][r]; vb = vb > 0.f ? vb : 0.f;
                e0[r] = __expf(va);
                e1[r] = __expf(vb);
            }
            ep[0][pt].x = pk2(e0[0], e0[1]); ep[0][pt].y = pk2(e0[2], e0[3]);
            ep[1][pt].x = pk2(e1[0], e1[1]); ep[1][pt].y = pk2(e1[2], e1[3]);
        }
    }

    // ------- epilogue: o = e * deninv * (s + cnt*b3), no barrier -----------
    const int rh = (h == 0 || h == 63) ? 2 : 3;
    f4 b3v[2];
    #pragma unroll
    for (int ft = 0; ft < 2; ++ft)
        b3v[ft] = *(const f4*)(b3 + F0 + ft * 16 + lkg * 4);
    #pragma unroll
    for (int pt = 0; pt < 4; ++pt) {
        int px = pt * 16 + cl;
        float is = isv[pt];
        float cnt = (float)(rh * ((px == 0 || px == 63) ? 2 : 3));
        #pragma unroll
        for (int ft = 0; ft < 2; ++ft) {
            int f0 = F0 + ft * 16 + lkg * 4;
            uint2 ev = ep[ft][pt];
            f4 o;
            o.x = bf2f(ev.x & 0xffffu) * is * (acc[ft][pt][0] + cnt * b3v[ft].x);
            o.y = bf2f(ev.x >> 16)     * is * (acc[ft][pt][1] + cnt * b3v[ft].y);
            o.z = bf2f(ev.y & 0xffffu) * is * (acc[ft][pt][2] + cnt * b3v[ft].z);
            o.w = bf2f(ev.y >> 16)     * is * (acc[ft][pt][3] + cnt * b3v[ft].w);
            *(f4*)(out + rowb + (size_t)px * 256 + f0) = o;
        }
    }
}

extern "C" void kernel_launch(void* const* d_in, const int* in_sizes, int n_in,
                              void* d_out, int out_size, void* d_ws, size_t ws_size,
                              hipStream_t stream)
{
    const float* x   = (const float*)d_in[0];
    const float* w3  = (const float*)d_in[1];
    const float* b3  = (const float*)d_in[2];
    const float* g1  = (const float*)d_in[3];
    const float* be1 = (const float*)d_in[4];
    const float* m1  = (const float*)d_in[5];
    const float* v1  = (const float*)d_in[6];
    const float* wa1 = (const float*)d_in[7];
    const float* ba1 = (const float*)d_in[8];
    const float* g2  = (const float*)d_in[9];
    const float* be2 = (const float*)d_in[10];
    const float* m2  = (const float*)d_in[11];
    const float* v2  = (const float*)d_in[12];
    const float* wa2 = (const float*)d_in[13];
    const float* ba2 = (const float*)d_in[14];

    unsigned char* ws = (unsigned char*)d_ws;
    unsigned short* w3T    = (unsigned short*)(ws);
    unsigned short* wa1T   = (unsigned short*)(ws + 131072);
    unsigned short* wa2T   = (unsigned short*)(ws + 147456);
    float*          b_a1p  = (float*)(ws + 163840);
    float*          b_a2p  = (float*)(ws + 163968);
    unsigned short* a1g    = (unsigned short*)(ws + 196608);             // 4 MB
    float*          deninv = (float*)(ws + 196608 + 4194304);            // 256 KB

    hipLaunchKernelGGL(prep_kernel, dim3(97), dim3(256), 0, stream,
                       w3, g1, be1, m1, v1, wa1, ba1, g2, be2, m2, v2, wa2, ba2,
                       w3T, wa1T, wa2T, b_a1p, b_a2p);
    hipLaunchKernelGGL(attn1_kernel, dim3(1024), dim3(256), 0, stream,
                       x, wa1T, wa2T, b_a1p, b_a2p, a1g, deninv);
    hipLaunchKernelGGL(fused2_kernel, dim3(1024), dim3(512), 0, stream,
                       x, a1g, b3, w3T, wa2T, b_a2p, deninv, (float*)d_out);
}

// Round 14
// 73.243 us; speedup vs baseline: 1.3259x; 1.0251x over previous
//
#include <hip/hip_runtime.h>
#include <hip/hip_bf16.h>

#define EPS 1e-3f

typedef float f32x4 __attribute__((ext_vector_type(4)));
typedef float f4    __attribute__((ext_vector_type(4)));
typedef short short8 __attribute__((ext_vector_type(8)));

__device__ __forceinline__ unsigned short f2bf(float f) {
    unsigned u = __float_as_uint(f);
    u += 0x7FFFu + ((u >> 16) & 1u);   // round-to-nearest-even
    return (unsigned short)(u >> 16);
}
__device__ __forceinline__ float bf2f(unsigned s) {
    return __uint_as_float(s << 16);
}
// packed f32x2 -> bf16x2 (RNE)
__device__ __forceinline__ unsigned pk2(float lo, float hi) {
    float2 t; t.x = lo; t.y = hi;
    __hip_bfloat162 hh = __float22bfloat162_rn(t);
    return *reinterpret_cast<unsigned*>(&hh);
}

// ---------------------------------------------------------------------------
// Prep: fold BN1/BN2 into attention weights, transpose all weights to bf16
// ---------------------------------------------------------------------------
__global__ void prep_kernel(const float* __restrict__ w3,
                            const float* __restrict__ g1, const float* __restrict__ be1,
                            const float* __restrict__ m1, const float* __restrict__ v1,
                            const float* __restrict__ wa1, const float* __restrict__ ba1,
                            const float* __restrict__ g2, const float* __restrict__ be2,
                            const float* __restrict__ m2, const float* __restrict__ v2,
                            const float* __restrict__ wa2, const float* __restrict__ ba2,
                            unsigned short* __restrict__ w3T,
                            unsigned short* __restrict__ wa1T,
                            unsigned short* __restrict__ wa2T,
                            float* __restrict__ b_a1p, float* __restrict__ b_a2p)
{
    const int blk = blockIdx.x;
    const int tid = threadIdx.x;
    if (blk < 64) {
        #pragma unroll
        for (int i = 0; i < 4; ++i) {
            int f = blk * 4 + i;
            w3T[f * 256 + tid] = f2bf(w3[tid * 256 + f]);
        }
    } else if (blk < 96) {
        int a = blk - 64;
        int c = tid;
        float s1 = rsqrtf(v1[c] + EPS) * g1[c];
        float wv = wa1[c * 32 + a];
        wa1T[a * 256 + c] = f2bf(wv * s1);
        float part = (be1[c] - m1[c] * s1) * wv;
        __shared__ float red[4];
        #pragma unroll
        for (int off = 32; off > 0; off >>= 1) part += __shfl_down(part, off);
        if ((tid & 63) == 0) red[tid >> 6] = part;
        __syncthreads();
        if (tid == 0) b_a1p[a] = ba1[a] + red[0] + red[1] + red[2] + red[3];
    } else {
        int f = tid;
        float acc = ba2[f];
        #pragma unroll
        for (int a = 0; a < 32; ++a) {
            float s2 = rsqrtf(v2[a] + EPS) * g2[a];
            float wv = wa2[a * 256 + f];
            wa2T[f * 32 + a] = f2bf(wv * s2);
            acc += (be2[a] - m2[a] * s2) * wv;
        }
        b_a2p[f] = acc;
    }
}

// ---------------------------------------------------------------------------
// Kernel A: a1 = relu(x_bn @ wa1') (bf16 ws) + deninv[px] = 1/sum_f e (f32).
// Block = one image row, 4 waves x 16 px.  x row staged to LDS COALESCED
// (1 KB per wave-instruction) so GEMM1 A-frags come from LDS, not 64-segment
// global gathers.  LDS 37888: xbf[0,32768) swizzled; bounce[32768,37888).
// ---------------------------------------------------------------------------
__global__ __launch_bounds__(256, 4)
void attn1_kernel(const float* __restrict__ x,
                  const unsigned short* __restrict__ wa1T,
                  const unsigned short* __restrict__ wa2T,
                  const float* __restrict__ b_a1p,
                  const float* __restrict__ b_a2p,
                  unsigned short* __restrict__ a1g,
                  float* __restrict__ deninv_g)
{
    __shared__ __align__(16) unsigned char lds[37888];

    const int tid = threadIdx.x;
    const int bid = blockIdx.x;
    const int row = (bid & 7) * 128 + (bid >> 3);   // XCD swizzle

    const int wv   = tid >> 6;
    const int lane = tid & 63;
    const int cl   = lane & 15;
    const int lkg  = lane >> 4;

    // ------- stage x row -> LDS bf16 (coalesced reads) ---------------------
    const f4* pc = (const f4*)(x + (size_t)row * 16384);
    #pragma unroll
    for (int j = 0; j < 16; ++j) {
        int v  = tid + j * 256;        // f4 index 0..4095
        int px = v >> 6;
        int c4 = v & 63;
        f4 a0 = pc[v];
        uint2 pb;
        pb.x = pk2(a0.x, a0.y);
        pb.y = pk2(a0.z, a0.w);
        unsigned ad = (unsigned)px * 512u +
                      (((unsigned)c4 * 8u) ^ (((unsigned)px & 7u) << 4));
        *(uint2*)(lds + ad) = pb;
    }
    __syncthreads();

    // ------- GEMM1: A from LDS -------------------------------------------
    const int arow = wv * 16 + cl;
    f32x4 acc1[2];
    acc1[0] = (f32x4){0,0,0,0};
    acc1[1] = (f32x4){0,0,0,0};
    #pragma unroll
    for (int kk = 0; kk < 8; ++kk) {
        unsigned ad = (unsigned)arow * 512u +
                      (((unsigned)(kk * 64 + lkg * 16)) ^ (((unsigned)arow & 7u) << 4));
        short8 afr = *(const short8*)(lds + ad);
        #pragma unroll
        for (int t = 0; t < 2; ++t) {
            short8 bfr = *(const short8*)(wa1T + ((t * 16 + cl) * 256 + kk * 32 + lkg * 8));
            acc1[t] = __builtin_amdgcn_mfma_f32_16x16x32_bf16(afr, bfr, acc1[t], 0, 0, 0);
        }
    }
    // bounce (pitch 80), coalesced a1g store
    const unsigned a1base = 32768u + (unsigned)wv * 1280u;
    #pragma unroll
    for (int t = 0; t < 2; ++t) {
        int a = t * 16 + cl;
        float bb = b_a1p[a];
        #pragma unroll
        for (int r = 0; r < 4; ++r) {
            float vv = acc1[t][r] + bb;
            vv = vv > 0.f ? vv : 0.f;
            int m = lkg * 4 + r;
            *(unsigned short*)(lds + a1base + m * 80 + a * 2) = f2bf(vv);
        }
    }
    asm volatile("s_waitcnt lgkmcnt(0)" ::: "memory");
    __builtin_amdgcn_sched_barrier(0);
    uint4 v = *(const uint4*)(lds + a1base + (lane >> 2) * 80 + (lane & 3) * 16);
    *(uint4*)(a1g + (size_t)row * 2048 + wv * 512 + lane * 8) = v;

    // ------- GEMM2 full-f for own 16 px -> deninv (bf16-rounded a1) --------
    {
        short8 a1f = *(const short8*)(lds + a1base + cl * 80 + lkg * 16);
        float ssum = 0.f;
        #pragma unroll
        for (int t = 0; t < 16; ++t) {
            short8 wfr = *(const short8*)(wa2T + ((t * 16 + cl) * 32 + lkg * 8));
            f32x4 z = {0, 0, 0, 0};
            f32x4 a2 = __builtin_amdgcn_mfma_f32_16x16x32_bf16(wfr, a1f, z, 0, 0, 0);
            f4 bb = *(const f4*)(b_a2p + t * 16 + lkg * 4);
            float v0 = a2[0] + bb.x; v0 = v0 > 0.f ? v0 : 0.f;
            float v1 = a2[1] + bb.y; v1 = v1 > 0.f ? v1 : 0.f;
            float v2 = a2[2] + bb.z; v2 = v2 > 0.f ? v2 : 0.f;
            float v3 = a2[3] + bb.w; v3 = v3 > 0.f ? v3 : 0.f;
            ssum += (__expf(v0) + __expf(v1)) + (__expf(v2) + __expf(v3));
        }
        ssum += __shfl_xor(ssum, 16);
        ssum += __shfl_xor(ssum, 32);
        if (lkg == 0)
            deninv_g[row * 64 + wv * 16 + cl] = 1.f / ssum;
    }
}

// ---------------------------------------------------------------------------
// Kernel B: stage | B1 | merged {main GEMM + GEMM2/exp} | B2 | epilogue via
// LDS-bounce in 2 half-row rounds -> ALL global stores perfectly coalesced
// (1 KB contiguous per wave-instruction; previously 64x16B scatter = the
// hidden 27 us).  Block = one image row, 8 waves; deninv precomputed.
// LDS 32768 reused: xs (phase 1) -> out-bounce [32 px][256 f] f32 (phase 2).
// ---------------------------------------------------------------------------
__global__ __launch_bounds__(512, 4)
void fused2_kernel(const float* __restrict__ x,
                   const unsigned short* __restrict__ a1g,
                   const float* __restrict__ b3,
                   const unsigned short* __restrict__ w3T,
                   const unsigned short* __restrict__ wa2T,
                   const float* __restrict__ b_a2p,
                   const float* __restrict__ deninv_g,
                   float* __restrict__ out)
{
    __shared__ __align__(16) unsigned char lds[32768];

    const int tid = threadIdx.x;
    const int bid = blockIdx.x;
    const int row = (bid & 7) * 128 + (bid >> 3);   // XCD swizzle
    const int h   = row & 63;

    const int wv   = tid >> 6;
    const int lane = tid & 63;
    const int cl   = lane & 15;
    const int lkg  = lane >> 4;
    const int F0   = wv * 32;

    const size_t rowb = (size_t)row * 16384;
    const float* xrow = x + rowb;
    const bool hm = (h > 0), hp = (h < 63);
    const f4* pc = (const f4*)xrow;
    const f4* pm = (const f4*)(xrow - 16384);
    const f4* pp = (const f4*)(xrow + 16384);
    const f4 z4 = {0.f, 0.f, 0.f, 0.f};

    // ------- early: inverse denominators (coalesced 256B load) -------------
    float isv[4];
    #pragma unroll
    for (int pt = 0; pt < 4; ++pt)
        isv[pt] = deninv_g[row * 64 + pt * 16 + cl];

    // ------- stage own 8-px strip (coalesced) -> xs ------------------------
    {
        f4 lm[10], lc[10], lp[10];
        #pragma unroll
        for (int r = 0; r < 10; ++r) {
            int g  = wv * 8 - 1 + r;
            int gc = g < 0 ? 0 : (g > 63 ? 63 : g);
            int idx = gc * 64 + lane;
            lc[r] = pc[idx];
            lm[r] = hm ? pm[idx] : z4;
            lp[r] = hp ? pp[idx] : z4;
        }
        f4 vs[10];
        #pragma unroll
        for (int r = 0; r < 10; ++r) {
            int g = wv * 8 - 1 + r;
            f4 v = lm[r] + lc[r] + lp[r];
            vs[r] = (g >= 0 && g < 64) ? v : z4;
        }
        #pragma unroll
        for (int j = 0; j < 8; ++j) {
            f4 s = vs[j] + vs[j + 1] + vs[j + 2];
            int gw = wv * 8 + j;              // gw & 7 == j
            unsigned addr = (unsigned)gw * 512u +
                            (((unsigned)lane * 8u) ^ (((unsigned)j & 7u) << 4));
            uint2 pk;
            pk.x = pk2(s.x, s.y);
            pk.y = pk2(s.z, s.w);
            *(uint2*)(lds + addr) = pk;
        }
    }

    __syncthreads();   // B1: xs published

    // ------- merged region: main GEMM + GEMM2/exp interleaved --------------
    f32x4 acc[2][4];
    #pragma unroll
    for (int ft = 0; ft < 2; ++ft)
        #pragma unroll
        for (int pt = 0; pt < 4; ++pt) acc[ft][pt] = (f32x4){0,0,0,0};

    uint2 ep[2][4];                    // e packed bf16
    const unsigned short* a1row = a1g + (size_t)row * 2048;

    short8 wfr2[2];
    #pragma unroll
    for (int ft = 0; ft < 2; ++ft)
        wfr2[ft] = *(const short8*)(wa2T + ((F0 + ft * 16 + cl) * 32 + lkg * 8));
    f4 bb2[2];
    #pragma unroll
    for (int ft = 0; ft < 2; ++ft)
        bb2[ft] = *(const f4*)(b_a2p + F0 + ft * 16 + lkg * 4);

    #pragma unroll
    for (int kk = 0; kk < 8; ++kk) {
        short8 afr[2];
        #pragma unroll
        for (int ft = 0; ft < 2; ++ft)
            afr[ft] = *(const short8*)(w3T + ((F0 + ft * 16 + cl) * 256 + kk * 32 + lkg * 8));
        short8 xfr[4];
        #pragma unroll
        for (int pt = 0; pt < 4; ++pt) {
            unsigned px = (unsigned)(pt * 16 + cl);
            unsigned ad = px * 512u +
                          (((unsigned)(kk * 64 + lkg * 16)) ^ (((unsigned)px & 7u) << 4));
            xfr[pt] = *(const short8*)(lds + ad);
        }
        #pragma unroll
        for (int ft = 0; ft < 2; ++ft)
            #pragma unroll
            for (int pt = 0; pt < 4; ++pt)
                acc[ft][pt] = __builtin_amdgcn_mfma_f32_16x16x32_bf16(afr[ft], xfr[pt], acc[ft][pt], 0, 0, 0);

        if ((kk & 1) == 0) {
            const int pt = kk >> 1;
            short8 bfr = *(const short8*)(a1row + ((pt * 16 + cl) * 32 + lkg * 8));
            f32x4 z = {0,0,0,0};
            f32x4 a2a = __builtin_amdgcn_mfma_f32_16x16x32_bf16(wfr2[0], bfr, z, 0, 0, 0);
            f32x4 a2b = __builtin_amdgcn_mfma_f32_16x16x32_bf16(wfr2[1], bfr, z, 0, 0, 0);
            float e0[4], e1[4];
            #pragma unroll
            for (int r = 0; r < 4; ++r) {
                float va = a2a[r] + bb2[0][r]; va = va > 0.f ? va : 0.f;
                float vb = a2b[r] + bb2[1][r]; vb = vb > 0.f ? vb : 0.f;
                e0[r] = __expf(va);
                e1[r] = __expf(vb);
            }
            ep[0][pt].x = pk2(e0[0], e0[1]); ep[0][pt].y = pk2(e0[2], e0[3]);
            ep[1][pt].x = pk2(e1[0], e1[1]); ep[1][pt].y = pk2(e1[2], e1[3]);
        }
    }

    // ------- epilogue: 2 half-row rounds through LDS, coalesced stores -----
    const int rh = (h == 0 || h == 63) ? 2 : 3;
    f4 b3v[2];
    #pragma unroll
    for (int ft = 0; ft < 2; ++ft)
        b3v[ft] = *(const f4*)(b3 + F0 + ft * 16 + lkg * 4);

    #pragma unroll
    for (int ph2 = 0; ph2 < 2; ++ph2) {
        __syncthreads();   // xs reads done (round 0) / readback done (round 1)
        // write phase: this wave's C fragments for px in [ph2*32, ph2*32+32)
        #pragma unroll
        for (int q = 0; q < 2; ++q) {
            int pt  = ph2 * 2 + q;
            int px  = pt * 16 + cl;          // global px
            int lr  = q * 16 + cl;           // local LDS row 0..31
            float is = isv[pt];
            float cnt = (float)(rh * ((px == 0 || px == 63) ? 2 : 3));
            #pragma unroll
            for (int ft = 0; ft < 2; ++ft) {
                int f0 = F0 + ft * 16 + lkg * 4;
                uint2 ev = ep[ft][pt];
                f4 o;
                o.x = bf2f(ev.x & 0xffffu) * is * (acc[ft][pt][0] + cnt * b3v[ft].x);
                o.y = bf2f(ev.x >> 16)     * is * (acc[ft][pt][1] + cnt * b3v[ft].y);
                o.z = bf2f(ev.y & 0xffffu) * is * (acc[ft][pt][2] + cnt * b3v[ft].z);
                o.w = bf2f(ev.y >> 16)     * is * (acc[ft][pt][3] + cnt * b3v[ft].w);
                unsigned ad = (unsigned)lr * 1024u +
                              (((unsigned)f0 * 4u) ^ (((unsigned)px & 7u) << 4));
                *(f4*)(lds + ad) = o;
            }
        }
        __syncthreads();
        // readback phase: linear, perfectly coalesced global stores
        #pragma unroll
        for (int it = 0; it < 4; ++it) {
            int idx = it * 512 + tid;        // 16B unit 0..2047
            int pxr = idx >> 6;              // local row 0..31
            int inb = (idx & 63) * 16;       // byte in row
            int gpx = ph2 * 32 + pxr;
            unsigned ad = (unsigned)pxr * 1024u +
                          (((unsigned)inb) ^ (((unsigned)gpx & 7u) << 4));
            f4 o = *(const f4*)(lds + ad);
            *(f4*)(out + rowb + (size_t)gpx * 256 + (inb >> 2)) = o;
        }
    }
}

extern "C" void kernel_launch(void* const* d_in, const int* in_sizes, int n_in,
                              void* d_out, int out_size, void* d_ws, size_t ws_size,
                              hipStream_t stream)
{
    const float* x   = (const float*)d_in[0];
    const float* w3  = (const float*)d_in[1];
    const float* b3  = (const float*)d_in[2];
    const float* g1  = (const float*)d_in[3];
    const float* be1 = (const float*)d_in[4];
    const float* m1  = (const float*)d_in[5];
    const float* v1  = (const float*)d_in[6];
    const float* wa1 = (const float*)d_in[7];
    const float* ba1 = (const float*)d_in[8];
    const float* g2  = (const float*)d_in[9];
    const float* be2 = (const float*)d_in[10];
    const float* m2  = (const float*)d_in[11];
    const float* v2  = (const float*)d_in[12];
    const float* wa2 = (const float*)d_in[13];
    const float* ba2 = (const float*)d_in[14];

    unsigned char* ws = (unsigned char*)d_ws;
    unsigned short* w3T    = (unsigned short*)(ws);
    unsigned short* wa1T   = (unsigned short*)(ws + 131072);
    unsigned short* wa2T   = (unsigned short*)(ws + 147456);
    float*          b_a1p  = (float*)(ws + 163840);
    float*          b_a2p  = (float*)(ws + 163968);
    unsigned short* a1g    = (unsigned short*)(ws + 196608);             // 4 MB
    float*          deninv = (float*)(ws + 196608 + 4194304);            // 256 KB

    hipLaunchKernelGGL(prep_kernel, dim3(97), dim3(256), 0, stream,
                       w3, g1, be1, m1, v1, wa1, ba1, g2, be2, m2, v2, wa2, ba2,
                       w3T, wa1T, wa2T, b_a1p, b_a2p);
    hipLaunchKernelGGL(attn1_kernel, dim3(1024), dim3(256), 0, stream,
                       x, wa1T, wa2T, b_a1p, b_a2p, a1g, deninv);
    hipLaunchKernelGGL(fused2_kernel, dim3(1024), dim3(512), 0, stream,
                       x, a1g, b3, w3T, wa2T, b_a2p, deninv, (float*)d_out);
}